// Round 1
// baseline (302.330 us; speedup 1.0000x reference)
//
#include <hip/hip_runtime.h>
#include <hip/hip_bf16.h>

// Embedding gather: out[i, :] = embeddings[X[i], :]
// X: 4*8192 = 32768 int32 indices; embeddings: 50257 x 1024 fp32.
// One float4 per thread: row = gid >> 8, col4 = gid & 255 (1024 floats = 256 float4).
__global__ __launch_bounds__(256) void embedding_gather_kernel(
    const int* __restrict__ X,
    const float4* __restrict__ emb,   // viewed as float4: row stride = 256
    float4* __restrict__ out,         // viewed as float4
    int n_rows)
{
    const int row  = blockIdx.x;          // one block per output row
    const int col4 = threadIdx.x;         // 256 float4 per row
    if (row >= n_rows) return;
    const int idx = X[row];               // broadcast load (all lanes same addr)
    out[(size_t)row * 256 + col4] = emb[(size_t)idx * 256 + col4];
}

extern "C" void kernel_launch(void* const* d_in, const int* in_sizes, int n_in,
                              void* d_out, int out_size, void* d_ws, size_t ws_size,
                              hipStream_t stream) {
    const int*    X   = (const int*)d_in[0];
    const float4* emb = (const float4*)d_in[1];
    float4*       out = (float4*)d_out;
    const int n_rows = in_sizes[0];       // 32768
    embedding_gather_kernel<<<n_rows, 256, 0, stream>>>(X, emb, out, n_rows);
}